// Round 5
// baseline (169.438 us; speedup 1.0000x reference)
//
#include <hip/hip_runtime.h>

#define N_NODES 50000
#define N_EDGES 800000
#define D 128
#define NBUCK 196   // ceil(50000/256) buckets of 256 nodes (dst>>8)
#define CAP 4800    // per-bucket capacity; mean 4096, sigma ~64 -> 11 sigma
#define CHUNK 4096  // edges per passA block (4/thread at 1024 threads)
#define PA_BLKS ((N_EDGES + CHUNK - 1) / CHUNK)  // 196
#define FB_BLKS 3125                             // N_NODES*64/1024
#define WT_BLKS 16                               // 16384/1024
#define SWCAP 1024  // staged sw entries per agg block; 16 nodes ~ 256 +- 16

typedef __attribute__((ext_vector_type(8))) short short8;
typedef __attribute__((ext_vector_type(4))) float f32x4;

__device__ __forceinline__ unsigned short f2bf(float f) {
    unsigned u = __float_as_uint(f);
    u += 0x7fff + ((u >> 16) & 1);  // RNE
    return (unsigned short)(u >> 16);
}
__device__ __forceinline__ float lo16f(unsigned u) { return __uint_as_float(u << 16); }
__device__ __forceinline__ float hi16f(unsigned u) { return __uint_as_float(u & 0xffff0000u); }

// ---------------------------------------------------------------------------
// K1 (UNCHANGED from R4): passA per-block LDS histogram -> one global
// reservation per (block,bucket) -> contiguous ~21-entry runs (write
// merging), 1024 threads. fb/Wt conversion in the same grid.
// ---------------------------------------------------------------------------
__global__ __launch_bounds__(1024) void prep_passA(
    const float2* __restrict__ feat2, unsigned* __restrict__ fb,
    const float* __restrict__ W, unsigned short* __restrict__ Wt,
    const int* __restrict__ esrc, const int* __restrict__ edst,
    const float* __restrict__ ew, int* __restrict__ gcur,
    uint2* __restrict__ tmp) {
    __shared__ int lh[NBUCK], lbase[NBUCK], lcur[NBUCK];
    int blk = blockIdx.x, t = threadIdx.x;

    if (blk >= PA_BLKS) {
        int b2 = blk - PA_BLKS;
        if (b2 < FB_BLKS) {
            int i = b2 * 1024 + t;
            float2 f = feat2[i];
            fb[i] = (unsigned)f2bf(f.x) | ((unsigned)f2bf(f.y) << 16);
        } else {
            int idx = (b2 - FB_BLKS) * 1024 + t;  // 16384 weight elements
            int n = idx >> 7, k = idx & 127;
            Wt[idx] = f2bf(W[k * 128 + n]);
        }
        return;
    }

    // ---- passA ----
    for (int i = t; i < NBUCK; i += 1024) lh[i] = 0;
    __syncthreads();
    int e0 = blk * CHUNK;
    unsigned key[4];
    float wv[4];
#pragma unroll
    for (int j = 0; j < 4; ++j) {
        int e = e0 + j * 1024 + t;
        if (e < N_EDGES) {
            int src = esrc[e], dd = edst[e];
            key[j] = (unsigned)src | ((unsigned)(dd & 255) << 16) |
                     ((unsigned)(dd >> 8) << 24);
            wv[j] = ew[e];
            atomicAdd(&lh[dd >> 8], 1);
        } else key[j] = 0xff000000u;  // invalid bucket marker
    }
    __syncthreads();
    for (int i = t; i < NBUCK; i += 1024) {
        lbase[i] = atomicAdd(&gcur[i], lh[i]);
        lcur[i] = 0;
    }
    __syncthreads();
#pragma unroll
    for (int j = 0; j < 4; ++j) {
        int b = key[j] >> 24;
        if (b < NBUCK) {
            int r = atomicAdd(&lcur[b], 1);
            tmp[(size_t)b * CAP + lbase[b] + r] =
                make_uint2(key[j] & 0x00ffffffu, __float_as_uint(wv[j]));
        }
    }
}

// ---------------------------------------------------------------------------
// K2 (UNCHANGED from R4): per-bucket counting sort -> offsets[] +
// per-node-grouped sw, 1024 threads/block.
// ---------------------------------------------------------------------------
__global__ __launch_bounds__(1024) void passB(const int* __restrict__ gcur,
                                              const uint2* __restrict__ tmp,
                                              int* __restrict__ offsets,
                                              uint2* __restrict__ sw) {
    __shared__ int hist[256], ps[256];
    int b = blockIdx.x, t = threadIdx.x;

    // base = sum of gcur[0..b-1] (b <= 195 < 256: one entry per low thread)
    if (t < 256) ps[t] = (t < b) ? gcur[t] : 0;
    __syncthreads();
    for (int off = 128; off > 0; off >>= 1) {
        if (t < off) ps[t] += ps[t + off];
        __syncthreads();
    }
    int base = ps[0];
    int cnt = gcur[b];
    if (t < 256) hist[t] = 0;
    __syncthreads();

    const uint2* seg = tmp + (size_t)b * CAP;
    for (int i = t; i < cnt; i += 1024) atomicAdd(&hist[seg[i].x >> 16], 1);
    __syncthreads();

    int h = 0;
    if (t < 256) { h = hist[t]; ps[t] = h; }
    __syncthreads();
    for (int off = 1; off < 256; off <<= 1) {
        int x = 0;
        if (t < 256 && t >= off) x = ps[t - off];
        __syncthreads();
        if (t < 256) ps[t] += x;
        __syncthreads();
    }
    int o = 0;
    if (t < 256) {
        o = base + ps[t] - h;  // exclusive within-bucket + bucket base
        int node = b * 256 + t;
        if (node < N_NODES) offsets[node] = o;
    }
    if (b == NBUCK - 1 && t == 0) offsets[N_NODES] = N_EDGES;
    __syncthreads();
    if (t < 256) hist[t] = o;  // reuse as cursor
    __syncthreads();
    for (int i = t; i < cnt; i += 1024) {
        uint2 u = seg[i];
        int pos = atomicAdd(&hist[u.x >> 16], 1);
        sw[pos] = make_uint2(u.x & 0xffffu, u.y);
    }
}

// ---------------------------------------------------------------------------
// K3 (CHANGED): block = 16 nodes, wave aggregates 4. The block's entire sw
// range (~256 edges, binomial sigma 16; SWCAP=1024 = 48 sigma, global
// fallback beyond) is staged into LDS by one coalesced cooperative load.
// Per-node batches then read (src,w) via LDS broadcast (~120cy) instead of a
// dependent VMEM chain (~300-500cy), so the only VMEM latency per batch is
// the 16 row gathers; and dropping the pn[16] software-prefetch registers
// cuts peak VGPR (~110 -> ~80) to raise occupancy 4 -> 5-6 waves/SIMD.
// launch_bounds(256,4) caps VGPR at 128. All staged/fallback reads are
// guaranteed-valid sw entries (idx < e2 <= cnt), so no clamp masking needed
// except the tail's weight-zeroing. GEMM epilogue unchanged.
// mfma_f32_16x16x32_bf16: A[m=lane&15][k=quad*8+j], B[k][n=lane&15],
// D row=quad*4+reg, col=lane&15 (verified in prior rounds).
// ---------------------------------------------------------------------------
__global__ __launch_bounds__(256, 4) void agg_gemm(const int* __restrict__ offsets,
                                                   const uint2* __restrict__ sw,
                                                   const unsigned* __restrict__ fb,
                                                   const unsigned short* __restrict__ Wt,
                                                   float* __restrict__ out) {
    __shared__ unsigned Arows[16][68];
    __shared__ uint2 swl[SWCAP];
    __shared__ int soff[17];
    int t = threadIdx.x;
    int wave = t >> 6;
    int lane = t & 63;
    int row0 = blockIdx.x * 16;

    if (t < 17) soff[t] = offsets[row0 + t];
    __syncthreads();
    int base = soff[0];
    int cnt = soff[16] - base;
    int lim = cnt < SWCAP ? cnt : SWCAP;
    for (int i = t; i < lim; i += 256) swl[i] = sw[base + i];
    __syncthreads();

#pragma unroll 1
    for (int i = 0; i < 4; ++i) {
        int ni = wave * 4 + i;
        int n = row0 + ni;
        int b = soff[ni] - base, e2 = soff[ni + 1] - base;  // block-local
        unsigned us = fb[(size_t)n * 64 + lane];  // self row
        float ax = 0.f, ay = 0.f;
        int e = b;
        int nfull = (e2 - b) >> 4;

#pragma unroll 1
        for (int tt = 0; tt < nfull; ++tt) {
            uint2 p[16];
#pragma unroll
            for (int j = 0; j < 16; ++j) {
                int idx = e + j;
                p[j] = (idx < SWCAP) ? swl[idx] : sw[base + idx];
            }
            unsigned u[16];
#pragma unroll
            for (int j = 0; j < 16; ++j) u[j] = fb[(size_t)p[j].x * 64 + lane];
#pragma unroll
            for (int j = 0; j < 16; ++j) {
                float w = __uint_as_float(p[j].y);
                ax += w * lo16f(u[j]);
                ay += w * hi16f(u[j]);
            }
            e += 16;
        }
        int rem = e2 - e;
        if (rem > 0) {  // tail: clamp to last real edge, zero the pad weights
            uint2 p[16];
#pragma unroll
            for (int j = 0; j < 16; ++j) {
                int idx = e + ((j < rem) ? j : rem - 1);
                p[j] = (idx < SWCAP) ? swl[idx] : sw[base + idx];
            }
            unsigned u[16];
#pragma unroll
            for (int j = 0; j < 16; ++j) u[j] = fb[(size_t)p[j].x * 64 + lane];
#pragma unroll
            for (int j = 0; j < 16; ++j) {
                float w = (j < rem) ? __uint_as_float(p[j].y) : 0.f;
                ax += w * lo16f(u[j]);
                ay += w * hi16f(u[j]);
            }
        }
        float rx = 0.5f * (ax + lo16f(us));
        float ry = 0.5f * (ay + hi16f(us));
        Arows[ni][lane] = (unsigned)f2bf(rx) | ((unsigned)f2bf(ry) << 16);
    }
    __syncthreads();

    int quad = lane >> 4;
    int col  = lane & 15;
    short8 a[4];
#pragma unroll
    for (int kk = 0; kk < 4; ++kk)
        a[kk] = *reinterpret_cast<const short8*>(&Arows[col][kk * 16 + quad * 4]);

#pragma unroll
    for (int ii = 0; ii < 2; ++ii) {
        int n0 = wave * 2 + ii;
        const short8* bp = reinterpret_cast<const short8*>(Wt) + ((n0 * 16 + col) * 16 + quad);
        f32x4 acc = {0.f, 0.f, 0.f, 0.f};
        acc = __builtin_amdgcn_mfma_f32_16x16x32_bf16(a[0], bp[0],  acc, 0, 0, 0);
        acc = __builtin_amdgcn_mfma_f32_16x16x32_bf16(a[1], bp[4],  acc, 0, 0, 0);
        acc = __builtin_amdgcn_mfma_f32_16x16x32_bf16(a[2], bp[8],  acc, 0, 0, 0);
        acc = __builtin_amdgcn_mfma_f32_16x16x32_bf16(a[3], bp[12], acc, 0, 0, 0);
#pragma unroll
        for (int rr = 0; rr < 4; ++rr)
            out[(size_t)(row0 + quad * 4 + rr) * D + n0 * 16 + col] = acc[rr];
    }
}

// ---------------------------------------------------------------------------
extern "C" void kernel_launch(void* const* d_in, const int* in_sizes, int n_in,
                              void* d_out, int out_size, void* d_ws, size_t ws_size,
                              hipStream_t stream) {
    const float* feat = (const float*)d_in[0];
    const int*   esrc = (const int*)d_in[1];
    const int*   edst = (const int*)d_in[2];
    const float* ew   = (const float*)d_in[3];
    const float* W    = (const float*)d_in[4];
    float*       out  = (float*)d_out;

    char* ws = (char*)d_ws;
    uint2*          sw      = (uint2*)(ws + 0);                   //  6,400,000
    unsigned*       fb      = (unsigned*)(ws + 6400000);          // 12,800,000
    int*            offsets = (int*)(ws + 19200000);              //    200,004
    unsigned short* Wt      = (unsigned short*)(ws + 19400064);   //     32,768
    int*            gcur    = (int*)(ws + 19432832);              //        784
    // tmp (7.53 MB) aliases d_out, dead until agg_gemm overwrites it.
    uint2* tmp = (uint2*)d_out;

    hipMemsetAsync(gcur, 0, NBUCK * sizeof(int), stream);
    prep_passA<<<PA_BLKS + FB_BLKS + WT_BLKS, 1024, 0, stream>>>(
        (const float2*)feat, fb, W, Wt, esrc, edst, ew, gcur, tmp);
    passB<<<NBUCK, 1024, 0, stream>>>(gcur, tmp, offsets, sw);
    agg_gemm<<<N_NODES / 16, 256, 0, stream>>>(offsets, sw, fb, Wt, out);
}

// Round 6
// 147.398 us; speedup vs baseline: 1.1495x; 1.1495x over previous
//
#include <hip/hip_runtime.h>

#define N_NODES 50000
#define N_EDGES 800000
#define D 128
#define NBUCK 196   // ceil(50000/256) buckets of 256 nodes (dst>>8)
#define CAP 4800    // per-bucket capacity; mean 4096, sigma ~64 -> 11 sigma
#define CHUNK 4096  // edges per passA block (4/thread at 1024 threads)
#define PA_BLKS ((N_EDGES + CHUNK - 1) / CHUNK)  // 196
#define FB_BLKS 3125                             // N_NODES*64/1024
#define WT_BLKS 16                               // 16384/1024
#define GSTRIDE 16  // gcur padding: 1 counter per 64B line -> reservation
                    // atomics spread across L2 slices instead of 13 lines

typedef __attribute__((ext_vector_type(8))) short short8;
typedef __attribute__((ext_vector_type(4))) float f32x4;

__device__ __forceinline__ unsigned short f2bf(float f) {
    unsigned u = __float_as_uint(f);
    u += 0x7fff + ((u >> 16) & 1);  // RNE
    return (unsigned short)(u >> 16);
}
__device__ __forceinline__ float lo16f(unsigned u) { return __uint_as_float(u << 16); }
__device__ __forceinline__ float hi16f(unsigned u) { return __uint_as_float(u & 0xffff0000u); }

// ---------------------------------------------------------------------------
// K1: passA per-block LDS histogram -> one global reservation per
// (block,bucket) -> contiguous ~21-entry runs (write merging), 1024 threads.
// CHANGED vs R4: gcur padded to 64B/counter (GSTRIDE) so the 196x196
// device-scope reservation atomics don't serialize on ~13 cache lines.
// fb/Wt conversion in the same grid.
// ---------------------------------------------------------------------------
__global__ __launch_bounds__(1024) void prep_passA(
    const float2* __restrict__ feat2, unsigned* __restrict__ fb,
    const float* __restrict__ W, unsigned short* __restrict__ Wt,
    const int* __restrict__ esrc, const int* __restrict__ edst,
    const float* __restrict__ ew, int* __restrict__ gcur,
    uint2* __restrict__ tmp) {
    __shared__ int lh[NBUCK], lbase[NBUCK], lcur[NBUCK];
    int blk = blockIdx.x, t = threadIdx.x;

    if (blk >= PA_BLKS) {
        int b2 = blk - PA_BLKS;
        if (b2 < FB_BLKS) {
            int i = b2 * 1024 + t;
            float2 f = feat2[i];
            fb[i] = (unsigned)f2bf(f.x) | ((unsigned)f2bf(f.y) << 16);
        } else {
            int idx = (b2 - FB_BLKS) * 1024 + t;  // 16384 weight elements
            int n = idx >> 7, k = idx & 127;
            Wt[idx] = f2bf(W[k * 128 + n]);
        }
        return;
    }

    // ---- passA ----
    for (int i = t; i < NBUCK; i += 1024) lh[i] = 0;
    __syncthreads();
    int e0 = blk * CHUNK;
    unsigned key[4];
    float wv[4];
#pragma unroll
    for (int j = 0; j < 4; ++j) {
        int e = e0 + j * 1024 + t;
        if (e < N_EDGES) {
            int src = esrc[e], dd = edst[e];
            key[j] = (unsigned)src | ((unsigned)(dd & 255) << 16) |
                     ((unsigned)(dd >> 8) << 24);
            wv[j] = ew[e];
            atomicAdd(&lh[dd >> 8], 1);
        } else key[j] = 0xff000000u;  // invalid bucket marker
    }
    __syncthreads();
    for (int i = t; i < NBUCK; i += 1024) {
        lbase[i] = atomicAdd(&gcur[i * GSTRIDE], lh[i]);
        lcur[i] = 0;
    }
    __syncthreads();
#pragma unroll
    for (int j = 0; j < 4; ++j) {
        int b = key[j] >> 24;
        if (b < NBUCK) {
            int r = atomicAdd(&lcur[b], 1);
            tmp[(size_t)b * CAP + lbase[b] + r] =
                make_uint2(key[j] & 0x00ffffffu, __float_as_uint(wv[j]));
        }
    }
}

// ---------------------------------------------------------------------------
// K2: per-bucket counting sort -> offsets[] + per-node-grouped sw, 1024
// threads/block. CHANGED vs R4: reads padded gcur; seg entries cached in
// registers between histogram and scatter (statically-indexed ent[5], no
// scratch) -> 6.4MB of L2 re-reads removed.
// ---------------------------------------------------------------------------
__global__ __launch_bounds__(1024) void passB(const int* __restrict__ gcur,
                                              const uint2* __restrict__ tmp,
                                              int* __restrict__ offsets,
                                              uint2* __restrict__ sw) {
    __shared__ int hist[256], ps[256];
    int b = blockIdx.x, t = threadIdx.x;

    // base = sum of gcur[0..b-1] (b <= 195 < 256: one entry per low thread)
    if (t < 256) ps[t] = (t < b) ? gcur[t * GSTRIDE] : 0;
    __syncthreads();
    for (int off = 128; off > 0; off >>= 1) {
        if (t < off) ps[t] += ps[t + off];
        __syncthreads();
    }
    int base = ps[0];
    int cnt = gcur[b * GSTRIDE];
    if (t < 256) hist[t] = 0;
    __syncthreads();

    const uint2* seg = tmp + (size_t)b * CAP;
    uint2 ent[5];
#pragma unroll
    for (int j = 0; j < 5; ++j) {
        int i = t + j * 1024;
        if (i < cnt) {
            ent[j] = seg[i];
            atomicAdd(&hist[ent[j].x >> 16], 1);
        }
    }
    __syncthreads();

    int h = 0;
    if (t < 256) { h = hist[t]; ps[t] = h; }
    __syncthreads();
    for (int off = 1; off < 256; off <<= 1) {
        int x = 0;
        if (t < 256 && t >= off) x = ps[t - off];
        __syncthreads();
        if (t < 256) ps[t] += x;
        __syncthreads();
    }
    int o = 0;
    if (t < 256) {
        o = base + ps[t] - h;  // exclusive within-bucket + bucket base
        int node = b * 256 + t;
        if (node < N_NODES) offsets[node] = o;
    }
    if (b == NBUCK - 1 && t == 0) offsets[N_NODES] = N_EDGES;
    __syncthreads();
    if (t < 256) hist[t] = o;  // reuse as cursor
    __syncthreads();
#pragma unroll
    for (int j = 0; j < 5; ++j) {
        int i = t + j * 1024;
        if (i < cnt) {
            int pos = atomicAdd(&hist[ent[j].x >> 16], 1);
            sw[pos] = make_uint2(ent[j].x & 0xffffu, ent[j].y);
        }
    }
}

// ---------------------------------------------------------------------------
// K3 (BYTE-IDENTICAL to R4's proven 47us version; R5's LDS-staged variant
// regressed to 70us by killing the ~32-loads-in-flight register prefetch):
// block = 16 nodes, wave aggregates 4. __launch_bounds__(256,2) lifts the
// VGPR cap so p[16]+u[16]+pn[16] stay live. Tail batch clamp-padded with
// weights zeroed. Then blended bf16 rows -> Arows -> 16x128 @ 128x128 MFMA.
// mfma_f32_16x16x32_bf16: A[m=lane&15][k=quad*8+j], B[k][n=lane&15],
// D row=quad*4+reg, col=lane&15 (verified in prior rounds).
// ---------------------------------------------------------------------------
__global__ __launch_bounds__(256, 2) void agg_gemm(const int* __restrict__ offsets,
                                                   const uint2* __restrict__ sw,
                                                   const unsigned* __restrict__ fb,
                                                   const unsigned short* __restrict__ Wt,
                                                   float* __restrict__ out) {
    __shared__ unsigned Arows[16][68];
    int wave = threadIdx.x >> 6;
    int lane = threadIdx.x & 63;
    int row0 = blockIdx.x * 16;

#pragma unroll 1
    for (int i = 0; i < 4; ++i) {
        int n = __builtin_amdgcn_readfirstlane(row0 + wave * 4 + i);
        int b = offsets[n], e2 = offsets[n + 1];
        unsigned us = fb[(size_t)n * 64 + lane];  // self row
        float ax = 0.f, ay = 0.f;
        int e = b;
        int nfull = (e2 - b) >> 4;

        uint2 p[16];
        {   // preload first batch (clamped; OOB-safe: sw is followed by fb in ws)
            int rem = e2 - e;
#pragma unroll
            for (int j = 0; j < 16; ++j) {
                int idx = (j < rem) ? j : (rem > 0 ? rem - 1 : 0);
                p[j] = sw[e + idx];
            }
        }
#pragma unroll 1
        for (int t = 0; t < nfull; ++t) {
            unsigned u[16];
#pragma unroll
            for (int j = 0; j < 16; ++j) u[j] = fb[(size_t)p[j].x * 64 + lane];
            // prefetch next batch while the 16 gathers are in flight
            int en = e + 16;
            int rem = e2 - en;
            uint2 pn[16];
#pragma unroll
            for (int j = 0; j < 16; ++j) {
                int idx = (j < rem) ? j : (rem > 0 ? rem - 1 : 0);
                pn[j] = sw[en + idx];
            }
#pragma unroll
            for (int j = 0; j < 16; ++j) {
                float w = __uint_as_float(p[j].y);
                ax += w * lo16f(u[j]);
                ay += w * hi16f(u[j]);
            }
#pragma unroll
            for (int j = 0; j < 16; ++j) p[j] = pn[j];
            e = en;
        }
        int rem = e2 - e;
        if (rem > 0) {  // tail: p already holds the clamp-padded batch
            unsigned u[16];
#pragma unroll
            for (int j = 0; j < 16; ++j) u[j] = fb[(size_t)p[j].x * 64 + lane];
#pragma unroll
            for (int j = 0; j < 16; ++j) {
                float w = (j < rem) ? __uint_as_float(p[j].y) : 0.f;
                ax += w * lo16f(u[j]);
                ay += w * hi16f(u[j]);
            }
        }
        float rx = 0.5f * (ax + lo16f(us));
        float ry = 0.5f * (ay + hi16f(us));
        Arows[wave * 4 + i][lane] = (unsigned)f2bf(rx) | ((unsigned)f2bf(ry) << 16);
    }
    __syncthreads();

    int quad = lane >> 4;
    int col  = lane & 15;
    short8 a[4];
#pragma unroll
    for (int kk = 0; kk < 4; ++kk)
        a[kk] = *reinterpret_cast<const short8*>(&Arows[col][kk * 16 + quad * 4]);

#pragma unroll
    for (int ii = 0; ii < 2; ++ii) {
        int n0 = wave * 2 + ii;
        const short8* bp = reinterpret_cast<const short8*>(Wt) + ((n0 * 16 + col) * 16 + quad);
        f32x4 acc = {0.f, 0.f, 0.f, 0.f};
        acc = __builtin_amdgcn_mfma_f32_16x16x32_bf16(a[0], bp[0],  acc, 0, 0, 0);
        acc = __builtin_amdgcn_mfma_f32_16x16x32_bf16(a[1], bp[4],  acc, 0, 0, 0);
        acc = __builtin_amdgcn_mfma_f32_16x16x32_bf16(a[2], bp[8],  acc, 0, 0, 0);
        acc = __builtin_amdgcn_mfma_f32_16x16x32_bf16(a[3], bp[12], acc, 0, 0, 0);
#pragma unroll
        for (int rr = 0; rr < 4; ++rr)
            out[(size_t)(row0 + quad * 4 + rr) * D + n0 * 16 + col] = acc[rr];
    }
}

// ---------------------------------------------------------------------------
extern "C" void kernel_launch(void* const* d_in, const int* in_sizes, int n_in,
                              void* d_out, int out_size, void* d_ws, size_t ws_size,
                              hipStream_t stream) {
    const float* feat = (const float*)d_in[0];
    const int*   esrc = (const int*)d_in[1];
    const int*   edst = (const int*)d_in[2];
    const float* ew   = (const float*)d_in[3];
    const float* W    = (const float*)d_in[4];
    float*       out  = (float*)d_out;

    char* ws = (char*)d_ws;
    uint2*          sw      = (uint2*)(ws + 0);                   //  6,400,000
    unsigned*       fb      = (unsigned*)(ws + 6400000);          // 12,800,000
    int*            offsets = (int*)(ws + 19200000);              //    200,004
    unsigned short* Wt      = (unsigned short*)(ws + 19400064);   //     32,768
    int*            gcur    = (int*)(ws + 19432832);              //  12,544 (padded)
    // tmp (7.53 MB) aliases d_out, dead until agg_gemm overwrites it.
    uint2* tmp = (uint2*)d_out;

    hipMemsetAsync(gcur, 0, NBUCK * GSTRIDE * sizeof(int), stream);
    prep_passA<<<PA_BLKS + FB_BLKS + WT_BLKS, 1024, 0, stream>>>(
        (const float2*)feat, fb, W, Wt, esrc, edst, ew, gcur, tmp);
    passB<<<NBUCK, 1024, 0, stream>>>(gcur, tmp, offsets, sw);
    agg_gemm<<<N_NODES / 16, 256, 0, stream>>>(offsets, sw, fb, Wt, out);
}